// Round 3
// baseline (150.565 us; speedup 1.0000x reference)
//
#include <hip/hip_runtime.h>

typedef unsigned short u16;
typedef unsigned int u32;
typedef unsigned long long u64;
typedef short v8s __attribute__((ext_vector_type(8)));
typedef float v4f __attribute__((ext_vector_type(4)));

#define S_TOK 4096
#define MDIM  1024
#define NEXP  8
#define CAPN  1024

// ---------- helpers ----------
__device__ __forceinline__ u16 f2bf(float f) {
  u32 u = __float_as_uint(f);
  u += 0x7FFFu + ((u >> 16) & 1u);   // round-to-nearest-even
  return (u16)(u >> 16);
}
__device__ __forceinline__ float bf2f(u16 h) {
  return __uint_as_float(((u32)h) << 16);
}
__device__ __forceinline__ void gll16(const void* g, void* l) {
  __builtin_amdgcn_global_load_lds(
      (const __attribute__((address_space(1))) void*)g,
      (__attribute__((address_space(3))) void*)l, 16, 0, 0);
}

// ---------- 1. fused prep: blocks [0,1024) gate, [1024,3072) transw ----------
__global__ __launch_bounds__(256) void prep_kernel(const float* __restrict__ x,
                                                   const float* __restrict__ wg,
                                                   const float* __restrict__ w,
                                                   u16* __restrict__ xbf,
                                                   u16* __restrict__ wT,
                                                   int4* __restrict__ grec,
                                                   float* __restrict__ gpart) {
  __shared__ float smem[8224];
  int tid = threadIdx.x;
  int b = blockIdx.x;
  if (b < 1024) {
    // ---- gate: fp32 logits, softmax, top1/top2, fused x->bf16 ----
    float* wls = smem;                               // [e*1024 + m]
    float (*gsh)[NEXP] = (float (*)[NEXP])(smem + 8192);
    for (int i = tid; i < NEXP * MDIM; i += 256) {
      int m = i >> 3, e = i & 7;
      wls[e * MDIM + m] = wg[i];
    }
    __syncthreads();
    int wave = tid >> 6, lane = tid & 63;
    int s = b * 4 + wave;
    const float* xr = x + (size_t)s * MDIM;
    u16* xw = xbf + (size_t)s * MDIM;
    float acc[NEXP];
#pragma unroll
    for (int e = 0; e < NEXP; e++) acc[e] = 0.f;
#pragma unroll
    for (int j = 0; j < 16; j++) {
      int m = j * 64 + lane;
      float xv = xr[m];
      xw[m] = f2bf(xv);
#pragma unroll
      for (int e = 0; e < NEXP; e++) acc[e] = fmaf(xv, wls[e * MDIM + m], acc[e]);
    }
#pragma unroll
    for (int off = 32; off > 0; off >>= 1)
#pragma unroll
      for (int e = 0; e < NEXP; e++) acc[e] += __shfl_xor(acc[e], off, 64);

    if (lane == 0) {
      float mx = acc[0];
#pragma unroll
      for (int e = 1; e < NEXP; e++) mx = fmaxf(mx, acc[e]);
      float ex[NEXP], sum = 0.f;
#pragma unroll
      for (int e = 0; e < NEXP; e++) { ex[e] = expf(acc[e] - mx); sum += ex[e]; }
      float inv = 1.f / sum;
      int e1 = 0; float b1 = acc[0];
#pragma unroll
      for (int e = 1; e < NEXP; e++) if (acc[e] > b1) { b1 = acc[e]; e1 = e; }
      int e2 = -1; float b2 = -3.4e38f;
#pragma unroll
      for (int e = 0; e < NEXP; e++) if (e != e1 && acc[e] > b2) { b2 = acc[e]; e2 = e; }
      grec[s] = make_int4(e1, e2, __float_as_int(ex[e1] * inv), __float_as_int(ex[e2] * inv));
#pragma unroll
      for (int e = 0; e < NEXP; e++) gsh[wave][e] = ex[e] * inv;
    }
    __syncthreads();
    if (tid < NEXP)
      gpart[b * NEXP + tid] = gsh[0][tid] + gsh[1][tid] + gsh[2][tid] + gsh[3][tid];
  } else {
    // ---- transw: W [e][m][n] f32 -> W^T [e][n][m] bf16 ----
    int bb = b - 1024;
    int e  = bb >> 8;
    int mt = (bb >> 4) & 15;
    int nt = bb & 15;
    float (*tile)[65] = (float (*)[65])smem;
    const float* src = w + (size_t)e * MDIM * MDIM;
    u16* dst = wT + (size_t)e * MDIM * MDIM;
#pragma unroll
    for (int i = 0; i < 16; i++) {
      int idx = tid + i * 256;
      int r = idx >> 6, c = idx & 63;
      tile[r][c] = src[(size_t)(mt * 64 + r) * MDIM + nt * 64 + c];
    }
    __syncthreads();
#pragma unroll
    for (int i = 0; i < 16; i++) {
      int idx = tid + i * 256;
      int r = idx >> 6, c = idx & 63;
      dst[(size_t)(nt * 64 + r) * MDIM + mt * 64 + c] = f2bf(tile[c][r]);
    }
  }
}

// ---------- 2. scan: wave-shuffle cumsum, capacity drop, slots, init, l_aux ----------
__global__ __launch_bounds__(1024) void scan_kernel(const int4* __restrict__ grec,
                                                    int4* __restrict__ trec,
                                                    int* __restrict__ slot_token,
                                                    const float* __restrict__ gpart,
                                                    u16* __restrict__ zrow,
                                                    float* __restrict__ out) {
  __shared__ u64 wtot[16][4];
  __shared__ float gred[16][NEXP];
  int t = threadIdx.x, lane = t & 63, wave = t >> 6;

#pragma unroll
  for (int i = 0; i < 8; i++) slot_token[t + i * 1024] = -1;
  zrow[t] = 0;

  float4 p0 = ((const float4*)gpart)[t * 2];
  float4 p1 = ((const float4*)gpart)[t * 2 + 1];
  float gs[NEXP] = {p0.x, p0.y, p0.z, p0.w, p1.x, p1.y, p1.z, p1.w};
#pragma unroll
  for (int off = 32; off > 0; off >>= 1)
#pragma unroll
    for (int e = 0; e < NEXP; e++) gs[e] += __shfl_xor(gs[e], off, 64);
  if (lane == 0)
#pragma unroll
    for (int e = 0; e < NEXP; e++) gred[wave][e] = gs[e];

  int4 r[4];
#pragma unroll
  for (int i = 0; i < 4; i++) r[i] = grec[t * 4 + i];

  u64 a1 = 0, b1 = 0, a2 = 0, b2 = 0;
#pragma unroll
  for (int i = 0; i < 4; i++) {
    int x1 = r[i].x, x2 = r[i].y;
    if (x1 < 4) a1 += 1ULL << (x1 * 16); else b1 += 1ULL << ((x1 - 4) * 16);
    if (x2 < 4) a2 += 1ULL << (x2 * 16); else b2 += 1ULL << ((x2 - 4) * 16);
  }
  u64 ia1 = a1, ib1 = b1, ia2 = a2, ib2 = b2;
#pragma unroll
  for (int off = 1; off < 64; off <<= 1) {
    u64 s1 = __shfl_up(a1, off, 64), s2 = __shfl_up(b1, off, 64);
    u64 s3 = __shfl_up(a2, off, 64), s4 = __shfl_up(b2, off, 64);
    if (lane >= off) { a1 += s1; b1 += s2; a2 += s3; b2 += s4; }
  }
  if (lane == 63) { wtot[wave][0] = a1; wtot[wave][1] = b1; wtot[wave][2] = a2; wtot[wave][3] = b2; }
  __syncthreads();
  if (t < 16) {
    u64 v0 = wtot[t][0], v1 = wtot[t][1], v2 = wtot[t][2], v3 = wtot[t][3];
#pragma unroll
    for (int off = 1; off < 16; off <<= 1) {
      u64 s0 = __shfl_up(v0, off, 64), s1 = __shfl_up(v1, off, 64);
      u64 s2 = __shfl_up(v2, off, 64), s3 = __shfl_up(v3, off, 64);
      if (t >= off) { v0 += s0; v1 += s1; v2 += s2; v3 += s3; }
    }
    wtot[t][0] = v0; wtot[t][1] = v1; wtot[t][2] = v2; wtot[t][3] = v3;
  }
  __syncthreads();
  u64 o1 = 0, o2 = 0, o3 = 0, o4 = 0;
  if (wave > 0) { o1 = wtot[wave - 1][0]; o2 = wtot[wave - 1][1]; o3 = wtot[wave - 1][2]; o4 = wtot[wave - 1][3]; }
  u64 ea  = a1 + o1 - ia1;
  u64 eb  = b1 + o2 - ib1;
  u64 ea2 = a2 + o3 - ia2;
  u64 eb2 = b2 + o4 - ib2;
  u64 ta = wtot[15][0], tb = wtot[15][1];

  int base1[NEXP], base2[NEXP], cnt1[NEXP];
#pragma unroll
  for (int e = 0; e < 4; e++) {
    base1[e]     = (int)((ea  >> (e * 16)) & 0xFFFF);
    base1[4 + e] = (int)((eb  >> (e * 16)) & 0xFFFF);
    base2[e]     = (int)((ea2 >> (e * 16)) & 0xFFFF);
    base2[4 + e] = (int)((eb2 >> (e * 16)) & 0xFFFF);
    cnt1[e]      = (int)((ta  >> (e * 16)) & 0xFFFF);
    cnt1[4 + e]  = (int)((tb  >> (e * 16)) & 0xFFFF);
  }
#pragma unroll
  for (int i = 0; i < 4; i++) {
    int s = t * 4 + i;
    int e1 = r[i].x, e2 = r[i].y;
    float g1 = __int_as_float(r[i].z), g2 = __int_as_float(r[i].w);
    int l1 = 0, l2 = 0;
#pragma unroll
    for (int q = 0; q < NEXP; q++) {
      if (q == e1) { l1 = base1[q]; base1[q] = l1 + 1; }
      if (q == e2) { l2 = base2[q]; base2[q] = l2 + 1; }
    }
    int loc2 = l2 + cnt1[e2];
    bool k1 = l1 < CAPN;
    bool k2 = loc2 < CAPN;
    float g1s = k1 ? g1 : 0.f;
    float g2s = k2 ? g2 : 0.f;
    float denom = fmaxf(g1s + g2s, 1.1920929e-7f);
    float gn1 = g1s / denom, gn2 = g2s / denom;
    int slot1 = k1 ? e1 * CAPN + l1 : -1;
    int slot2 = k2 ? e2 * CAPN + loc2 : -1;
    trec[s] = make_int4(slot1, slot2, __float_as_int(gn1), __float_as_int(gn2));
    if (k1) slot_token[slot1] = s;
    if (k2) slot_token[slot2] = s;
  }
  if (t == 0) {
    float acc = 0.f;
#pragma unroll
    for (int e = 0; e < NEXP; e++) {
      float g = 0.f;
      for (int w2 = 0; w2 < 16; w2++) g += gred[w2][e];
      acc += g * (float)cnt1[e];
    }
    out[(size_t)S_TOK * MDIM] = 8.f * acc / (4096.f * 4096.f);
  }
}

// ---------- 3. expert GEMM: swizzled fragment-major LDS (conflict-free reads) ----------
// LDS tile layout: 16 groups of 1 KB. group g = m_tile*2 + ks (m_tile = m>>4, ks = kc>>2,
// kc = 8-elem k-chunk 0..7). Within group: chunk (m,kc) at ((kc&3)*16 + (m&15))*16 bytes.
// DMA dest is linear (base + lane*16); the permutation lives in the per-lane global source.
// Fragment read for (m_tile', ks): v8s index = g*64 + lane  -> lane-contiguous, conflict-free.
__global__ __launch_bounds__(256, 2) void expert_gemm(const u16* __restrict__ xbf,
                                                      const u16* __restrict__ wT,
                                                      const int* __restrict__ slot_token,
                                                      const u16* __restrict__ zrow,
                                                      const float* __restrict__ bias,
                                                      u16* __restrict__ eoutb) {
  __shared__ __align__(16) u16 As[128 * 64];
  __shared__ __align__(16) u16 Bs[128 * 64];
  const int tid  = threadIdx.x;
  const int e    = blockIdx.x >> 6;
  const int tile = blockIdx.x & 63;
  const int tm   = (tile >> 3) << 7;
  const int tn   = (tile & 7) << 7;
  const int lane = tid & 63;
  const int wave = tid >> 6;
  const int wr = wave >> 1, wc = wave & 1;

  const u16* srcA[4];
  const u16* srcB[4];
#pragma unroll
  for (int it = 0; it < 4; ++it) {
    int g     = it * 4 + wave;               // group 0..15 (uniform per wave-it)
    int m_loc = (g >> 1) * 16 + (lane & 15); // row within 128-tile
    int kc    = (g & 1) * 4 + (lane >> 4);   // 8-elem k-chunk within BK=64
    int st    = slot_token[e * CAPN + tm + m_loc];
    srcA[it] = (st >= 0 ? xbf + (size_t)st * MDIM : zrow) + kc * 8;
    srcB[it] = wT + (size_t)e * MDIM * MDIM + (size_t)(tn + m_loc) * MDIM + kc * 8;
  }
  char* ldsA = (char*)As;
  char* ldsB = (char*)Bs;

  v4f acc[4][4];
#pragma unroll
  for (int i = 0; i < 4; i++)
#pragma unroll
    for (int j = 0; j < 4; j++) acc[i][j] = (v4f){0.f, 0.f, 0.f, 0.f};

  for (int k0 = 0; k0 < MDIM; k0 += 64) {
    __syncthreads();
#pragma unroll
    for (int it = 0; it < 4; ++it)
      gll16(srcA[it] + k0, ldsA + tid * 16 + it * 4096);
#pragma unroll
    for (int it = 0; it < 4; ++it)
      gll16(srcB[it] + k0, ldsB + tid * 16 + it * 4096);
    __syncthreads();

    const v8s* Ap = (const v8s*)As;
    const v8s* Bp = (const v8s*)Bs;
#pragma unroll
    for (int ks = 0; ks < 2; ++ks) {
      v8s af[4], bfr[4];
#pragma unroll
      for (int i = 0; i < 4; i++)
        af[i] = Ap[((wr * 4 + i) * 2 + ks) * 64 + lane];
#pragma unroll
      for (int j = 0; j < 4; j++)
        bfr[j] = Bp[((wc * 4 + j) * 2 + ks) * 64 + lane];
#pragma unroll
      for (int i = 0; i < 4; i++)
#pragma unroll
        for (int j = 0; j < 4; j++)
          acc[i][j] = __builtin_amdgcn_mfma_f32_16x16x32_bf16(af[i], bfr[j], acc[i][j], 0, 0, 0);
    }
  }

  const float* bp = bias + (size_t)e * MDIM;
  float bv[4];
#pragma unroll
  for (int j = 0; j < 4; j++) bv[j] = bp[tn + wc * 64 + j * 16 + (lane & 15)];
  u16* outp = eoutb + (size_t)e * CAPN * MDIM;
#pragma unroll
  for (int i = 0; i < 4; i++) {
#pragma unroll
    for (int rr = 0; rr < 4; rr++) {
      int row = tm + wr * 64 + i * 16 + (lane >> 4) * 4 + rr;
#pragma unroll
      for (int j = 0; j < 4; j++) {
        int col = tn + wc * 64 + j * 16 + (lane & 15);
        outp[(size_t)row * MDIM + col] = f2bf(acc[i][j][rr] + bv[j]);
      }
    }
  }
}

// ---------- 4. combine: y = g1*out1 + g2*out2 (bias folded into GEMM) ----------
__global__ __launch_bounds__(256) void combine_kernel(const u16* __restrict__ eoutb,
                                                      const int4* __restrict__ trec,
                                                      float* __restrict__ out) {
  int s = blockIdx.x;
  int tid = threadIdx.x;
  int4 r = trec[s];
  float g1 = __int_as_float(r.z), g2 = __int_as_float(r.w);
  float4 res = make_float4(0.f, 0.f, 0.f, 0.f);
  if (r.x >= 0) {
    ushort4 o = ((const ushort4*)(eoutb + (size_t)r.x * MDIM))[tid];
    res.x += g1 * bf2f(o.x); res.y += g1 * bf2f(o.y);
    res.z += g1 * bf2f(o.z); res.w += g1 * bf2f(o.w);
  }
  if (r.y >= 0) {
    ushort4 o = ((const ushort4*)(eoutb + (size_t)r.y * MDIM))[tid];
    res.x += g2 * bf2f(o.x); res.y += g2 * bf2f(o.y);
    res.z += g2 * bf2f(o.z); res.w += g2 * bf2f(o.w);
  }
  ((float4*)out)[(size_t)s * 256 + tid] = res;
}

// ---------- launcher ----------
extern "C" void kernel_launch(void* const* d_in, const int* in_sizes, int n_in,
                              void* d_out, int out_size, void* d_ws, size_t ws_size,
                              hipStream_t stream) {
  (void)in_sizes; (void)n_in; (void)out_size; (void)ws_size;
  const float* x  = (const float*)d_in[0];
  const float* wg = (const float*)d_in[1];
  const float* ew = (const float*)d_in[2];
  const float* eb = (const float*)d_in[3];
  float* out = (float*)d_out;

  char* ws = (char*)d_ws;
  u16*   xbf   = (u16*)(ws + 0);
  u16*   wT    = (u16*)(ws + 8388608);
  u16*   eoutb = (u16*)(ws + 25165824);
  u16*   zrow  = (u16*)(ws + 41943040);
  int4*  grec  = (int4*)(ws + 41945088);
  int4*  trec  = (int4*)(ws + 42010624);
  int*   slot  = (int*)(ws + 42076160);
  float* gpart = (float*)(ws + 42108928);

  prep_kernel<<<3072, 256, 0, stream>>>(x, wg, ew, xbf, wT, grec, gpart);
  scan_kernel<<<1, 1024, 0, stream>>>(grec, trec, slot, gpart, zrow, out);
  expert_gemm<<<512, 256, 0, stream>>>(xbf, wT, slot, zrow, eb, eoutb);
  combine_kernel<<<4096, 256, 0, stream>>>(eoutb, trec, out);
}

// Round 4
// 142.391 us; speedup vs baseline: 1.0574x; 1.0574x over previous
//
#include <hip/hip_runtime.h>

typedef unsigned short u16;
typedef unsigned int u32;
typedef unsigned long long u64;
typedef short v8s __attribute__((ext_vector_type(8)));
typedef float v4f __attribute__((ext_vector_type(4)));

#define S_TOK 4096
#define MDIM  1024
#define NEXP  8
#define CAPN  1024
#define PART_ELEMS (NEXP * CAPN * MDIM)   // one split-K partial buffer, bf16 elems

// ---------- helpers ----------
__device__ __forceinline__ u16 f2bf(float f) {
  u32 u = __float_as_uint(f);
  u += 0x7FFFu + ((u >> 16) & 1u);   // round-to-nearest-even
  return (u16)(u >> 16);
}
__device__ __forceinline__ float bf2f(u16 h) {
  return __uint_as_float(((u32)h) << 16);
}
__device__ __forceinline__ void gll16(const void* g, void* l) {
  __builtin_amdgcn_global_load_lds(
      (const __attribute__((address_space(1))) void*)g,
      (__attribute__((address_space(3))) void*)l, 16, 0, 0);
}

// ---------- 1. fused prep: blocks [0,1024) gate, [1024,3072) transw ----------
__global__ __launch_bounds__(256) void prep_kernel(const float* __restrict__ x,
                                                   const float* __restrict__ wg,
                                                   const float* __restrict__ w,
                                                   u16* __restrict__ xbf,
                                                   u16* __restrict__ wT,
                                                   int4* __restrict__ grec,
                                                   float* __restrict__ gpart) {
  __shared__ float smem[8224];
  int tid = threadIdx.x;
  int b = blockIdx.x;
  if (b < 1024) {
    // ---- gate: fp32 logits, softmax, top1/top2, fused x->bf16 ----
    float* wls = smem;                               // [e*1024 + m]
    float (*gsh)[NEXP] = (float (*)[NEXP])(smem + 8192);
    for (int i = tid; i < NEXP * MDIM; i += 256) {
      int m = i >> 3, e = i & 7;
      wls[e * MDIM + m] = wg[i];
    }
    __syncthreads();
    int wave = tid >> 6, lane = tid & 63;
    int s = b * 4 + wave;
    const float* xr = x + (size_t)s * MDIM;
    u16* xw = xbf + (size_t)s * MDIM;
    float acc[NEXP];
#pragma unroll
    for (int e = 0; e < NEXP; e++) acc[e] = 0.f;
#pragma unroll
    for (int j = 0; j < 16; j++) {
      int m = j * 64 + lane;
      float xv = xr[m];
      xw[m] = f2bf(xv);
#pragma unroll
      for (int e = 0; e < NEXP; e++) acc[e] = fmaf(xv, wls[e * MDIM + m], acc[e]);
    }
#pragma unroll
    for (int off = 32; off > 0; off >>= 1)
#pragma unroll
      for (int e = 0; e < NEXP; e++) acc[e] += __shfl_xor(acc[e], off, 64);

    if (lane == 0) {
      float mx = acc[0];
#pragma unroll
      for (int e = 1; e < NEXP; e++) mx = fmaxf(mx, acc[e]);
      float ex[NEXP], sum = 0.f;
#pragma unroll
      for (int e = 0; e < NEXP; e++) { ex[e] = expf(acc[e] - mx); sum += ex[e]; }
      float inv = 1.f / sum;
      int e1 = 0; float b1 = acc[0];
#pragma unroll
      for (int e = 1; e < NEXP; e++) if (acc[e] > b1) { b1 = acc[e]; e1 = e; }
      int e2 = -1; float b2 = -3.4e38f;
#pragma unroll
      for (int e = 0; e < NEXP; e++) if (e != e1 && acc[e] > b2) { b2 = acc[e]; e2 = e; }
      grec[s] = make_int4(e1, e2, __float_as_int(ex[e1] * inv), __float_as_int(ex[e2] * inv));
#pragma unroll
      for (int e = 0; e < NEXP; e++) gsh[wave][e] = ex[e] * inv;
    }
    __syncthreads();
    if (tid < NEXP)
      gpart[b * NEXP + tid] = gsh[0][tid] + gsh[1][tid] + gsh[2][tid] + gsh[3][tid];
  } else {
    // ---- transw: W [e][m][n] f32 -> W^T [e][n][m] bf16 ----
    int bb = b - 1024;
    int e  = bb >> 8;
    int mt = (bb >> 4) & 15;
    int nt = bb & 15;
    float (*tile)[65] = (float (*)[65])smem;
    const float* src = w + (size_t)e * MDIM * MDIM;
    u16* dst = wT + (size_t)e * MDIM * MDIM;
#pragma unroll
    for (int i = 0; i < 16; i++) {
      int idx = tid + i * 256;
      int r = idx >> 6, c = idx & 63;
      tile[r][c] = src[(size_t)(mt * 64 + r) * MDIM + nt * 64 + c];
    }
    __syncthreads();
#pragma unroll
    for (int i = 0; i < 16; i++) {
      int idx = tid + i * 256;
      int r = idx >> 6, c = idx & 63;
      dst[(size_t)(nt * 64 + r) * MDIM + mt * 64 + c] = f2bf(tile[c][r]);
    }
  }
}

// ---------- 2. scan: wave-shuffle cumsum, capacity drop, slots, init, l_aux ----------
__global__ __launch_bounds__(1024) void scan_kernel(const int4* __restrict__ grec,
                                                    int4* __restrict__ trec,
                                                    int* __restrict__ slot_token,
                                                    const float* __restrict__ gpart,
                                                    u16* __restrict__ zrow,
                                                    float* __restrict__ out) {
  __shared__ u64 wtot[16][4];
  __shared__ float gred[16][NEXP];
  int t = threadIdx.x, lane = t & 63, wave = t >> 6;

#pragma unroll
  for (int i = 0; i < 8; i++) slot_token[t + i * 1024] = -1;
  zrow[t] = 0;

  float4 p0 = ((const float4*)gpart)[t * 2];
  float4 p1 = ((const float4*)gpart)[t * 2 + 1];
  float gs[NEXP] = {p0.x, p0.y, p0.z, p0.w, p1.x, p1.y, p1.z, p1.w};
#pragma unroll
  for (int off = 32; off > 0; off >>= 1)
#pragma unroll
    for (int e = 0; e < NEXP; e++) gs[e] += __shfl_xor(gs[e], off, 64);
  if (lane == 0)
#pragma unroll
    for (int e = 0; e < NEXP; e++) gred[wave][e] = gs[e];

  int4 r[4];
#pragma unroll
  for (int i = 0; i < 4; i++) r[i] = grec[t * 4 + i];

  u64 a1 = 0, b1 = 0, a2 = 0, b2 = 0;
#pragma unroll
  for (int i = 0; i < 4; i++) {
    int x1 = r[i].x, x2 = r[i].y;
    if (x1 < 4) a1 += 1ULL << (x1 * 16); else b1 += 1ULL << ((x1 - 4) * 16);
    if (x2 < 4) a2 += 1ULL << (x2 * 16); else b2 += 1ULL << ((x2 - 4) * 16);
  }
  u64 ia1 = a1, ib1 = b1, ia2 = a2, ib2 = b2;
#pragma unroll
  for (int off = 1; off < 64; off <<= 1) {
    u64 s1 = __shfl_up(a1, off, 64), s2 = __shfl_up(b1, off, 64);
    u64 s3 = __shfl_up(a2, off, 64), s4 = __shfl_up(b2, off, 64);
    if (lane >= off) { a1 += s1; b1 += s2; a2 += s3; b2 += s4; }
  }
  if (lane == 63) { wtot[wave][0] = a1; wtot[wave][1] = b1; wtot[wave][2] = a2; wtot[wave][3] = b2; }
  __syncthreads();
  if (t < 16) {
    u64 v0 = wtot[t][0], v1 = wtot[t][1], v2 = wtot[t][2], v3 = wtot[t][3];
#pragma unroll
    for (int off = 1; off < 16; off <<= 1) {
      u64 s0 = __shfl_up(v0, off, 64), s1 = __shfl_up(v1, off, 64);
      u64 s2 = __shfl_up(v2, off, 64), s3 = __shfl_up(v3, off, 64);
      if (t >= off) { v0 += s0; v1 += s1; v2 += s2; v3 += s3; }
    }
    wtot[t][0] = v0; wtot[t][1] = v1; wtot[t][2] = v2; wtot[t][3] = v3;
  }
  __syncthreads();
  u64 o1 = 0, o2 = 0, o3 = 0, o4 = 0;
  if (wave > 0) { o1 = wtot[wave - 1][0]; o2 = wtot[wave - 1][1]; o3 = wtot[wave - 1][2]; o4 = wtot[wave - 1][3]; }
  u64 ea  = a1 + o1 - ia1;
  u64 eb  = b1 + o2 - ib1;
  u64 ea2 = a2 + o3 - ia2;
  u64 eb2 = b2 + o4 - ib2;
  u64 ta = wtot[15][0], tb = wtot[15][1];

  int base1[NEXP], base2[NEXP], cnt1[NEXP];
#pragma unroll
  for (int e = 0; e < 4; e++) {
    base1[e]     = (int)((ea  >> (e * 16)) & 0xFFFF);
    base1[4 + e] = (int)((eb  >> (e * 16)) & 0xFFFF);
    base2[e]     = (int)((ea2 >> (e * 16)) & 0xFFFF);
    base2[4 + e] = (int)((eb2 >> (e * 16)) & 0xFFFF);
    cnt1[e]      = (int)((ta  >> (e * 16)) & 0xFFFF);
    cnt1[4 + e]  = (int)((tb  >> (e * 16)) & 0xFFFF);
  }
#pragma unroll
  for (int i = 0; i < 4; i++) {
    int s = t * 4 + i;
    int e1 = r[i].x, e2 = r[i].y;
    float g1 = __int_as_float(r[i].z), g2 = __int_as_float(r[i].w);
    int l1 = 0, l2 = 0;
#pragma unroll
    for (int q = 0; q < NEXP; q++) {
      if (q == e1) { l1 = base1[q]; base1[q] = l1 + 1; }
      if (q == e2) { l2 = base2[q]; base2[q] = l2 + 1; }
    }
    int loc2 = l2 + cnt1[e2];
    bool k1 = l1 < CAPN;
    bool k2 = loc2 < CAPN;
    float g1s = k1 ? g1 : 0.f;
    float g2s = k2 ? g2 : 0.f;
    float denom = fmaxf(g1s + g2s, 1.1920929e-7f);
    float gn1 = g1s / denom, gn2 = g2s / denom;
    int slot1 = k1 ? e1 * CAPN + l1 : -1;
    int slot2 = k2 ? e2 * CAPN + loc2 : -1;
    trec[s] = make_int4(slot1, slot2, __float_as_int(gn1), __float_as_int(gn2));
    if (k1) slot_token[slot1] = s;
    if (k2) slot_token[slot2] = s;
  }
  if (t == 0) {
    float acc = 0.f;
#pragma unroll
    for (int e = 0; e < NEXP; e++) {
      float g = 0.f;
      for (int w2 = 0; w2 < 16; w2++) g += gred[w2][e];
      acc += g * (float)cnt1[e];
    }
    out[(size_t)S_TOK * MDIM] = 8.f * acc / (4096.f * 4096.f);
  }
}

// ---------- 3. expert GEMM, split-K x2: 1024 blocks, m97-style staging ----------
// Block bx: kh = bx>>9 (K half), e = (bx>>6)&7, tile = bx&63 (8x8 of 128x128).
// Partial C (bf16, no bias) goes to eoutb + kh*PART_ELEMS.
__global__ __launch_bounds__(256, 2) void expert_gemm(const u16* __restrict__ xbf,
                                                      const u16* __restrict__ wT,
                                                      const int* __restrict__ slot_token,
                                                      const u16* __restrict__ zrow,
                                                      u16* __restrict__ eoutb) {
  __shared__ __align__(16) u16 As[128 * 64];
  __shared__ __align__(16) u16 Bs[128 * 64];
  const int tid  = threadIdx.x;
  const int bx   = blockIdx.x;
  const int kh   = bx >> 9;
  const int e    = (bx >> 6) & 7;
  const int tile = bx & 63;
  const int tm   = (tile >> 3) << 7;
  const int tn   = (tile & 7) << 7;
  const int lane = tid & 63;
  const int wave = tid >> 6;
  const int wr = wave >> 1, wc = wave & 1;

  const u16* srcA[4];
  const u16* srcB[4];
#pragma unroll
  for (int it = 0; it < 4; ++it) {
    int off = tid * 16 + it * 4096;    // byte offset within 16 KB tile
    int row = off >> 7;                // 0..127
    int kb  = off & 127;               // byte offset in the 128B row-chunk
    int st  = slot_token[e * CAPN + tm + row];
    srcA[it] = (st >= 0 ? xbf + (size_t)st * MDIM : zrow) + (kb >> 1);
    srcB[it] = wT + (size_t)e * MDIM * MDIM + (size_t)(tn + row) * MDIM + (kb >> 1);
  }
  char* ldsA = (char*)As;
  char* ldsB = (char*)Bs;

  v4f acc[4][4];
#pragma unroll
  for (int i = 0; i < 4; i++)
#pragma unroll
    for (int j = 0; j < 4; j++) acc[i][j] = (v4f){0.f, 0.f, 0.f, 0.f};

  const int kbeg = kh * 512;
  for (int k0 = kbeg; k0 < kbeg + 512; k0 += 64) {
    __syncthreads();
#pragma unroll
    for (int it = 0; it < 4; ++it)
      gll16(srcA[it] + k0, ldsA + tid * 16 + it * 4096);
#pragma unroll
    for (int it = 0; it < 4; ++it)
      gll16(srcB[it] + k0, ldsB + tid * 16 + it * 4096);
    __syncthreads();

    const v8s* Ap = (const v8s*)As;
    const v8s* Bp = (const v8s*)Bs;
#pragma unroll
    for (int ks = 0; ks < 2; ++ks) {
      v8s af[4], bfr[4];
#pragma unroll
      for (int i = 0; i < 4; i++)
        af[i] = Ap[(wr * 64 + i * 16 + (lane & 15)) * 8 + ks * 4 + (lane >> 4)];
#pragma unroll
      for (int j = 0; j < 4; j++)
        bfr[j] = Bp[(wc * 64 + j * 16 + (lane & 15)) * 8 + ks * 4 + (lane >> 4)];
#pragma unroll
      for (int i = 0; i < 4; i++)
#pragma unroll
        for (int j = 0; j < 4; j++)
          acc[i][j] = __builtin_amdgcn_mfma_f32_16x16x32_bf16(af[i], bfr[j], acc[i][j], 0, 0, 0);
    }
  }

  u16* outp = eoutb + (size_t)kh * PART_ELEMS + (size_t)e * CAPN * MDIM;
#pragma unroll
  for (int i = 0; i < 4; i++) {
#pragma unroll
    for (int rr = 0; rr < 4; rr++) {
      int row = tm + wr * 64 + i * 16 + (lane >> 4) * 4 + rr;
#pragma unroll
      for (int j = 0; j < 4; j++) {
        int col = tn + wc * 64 + j * 16 + (lane & 15);
        outp[(size_t)row * MDIM + col] = f2bf(acc[i][j][rr]);
      }
    }
  }
}

// ---------- 4. combine: y = g1*(p0+p1+b)[slot1] + g2*(p0+p1+b)[slot2] ----------
__global__ __launch_bounds__(256) void combine_kernel(const u16* __restrict__ eoutb,
                                                      const int4* __restrict__ trec,
                                                      const float* __restrict__ bias,
                                                      float* __restrict__ out) {
  int s = blockIdx.x;
  int tid = threadIdx.x;
  int4 r = trec[s];
  float g1 = __int_as_float(r.z), g2 = __int_as_float(r.w);
  float4 res = make_float4(0.f, 0.f, 0.f, 0.f);
  const ushort4* p0 = (const ushort4*)eoutb;
  const ushort4* p1 = (const ushort4*)(eoutb + (size_t)PART_ELEMS);
  const float4*  b4 = (const float4*)bias;
  if (r.x >= 0) {
    ushort4 a = p0[(size_t)r.x * 256 + tid];
    ushort4 b = p1[(size_t)r.x * 256 + tid];
    float4  c = b4[(size_t)(r.x >> 10) * 256 + tid];
    res.x += g1 * (bf2f(a.x) + bf2f(b.x) + c.x);
    res.y += g1 * (bf2f(a.y) + bf2f(b.y) + c.y);
    res.z += g1 * (bf2f(a.z) + bf2f(b.z) + c.z);
    res.w += g1 * (bf2f(a.w) + bf2f(b.w) + c.w);
  }
  if (r.y >= 0) {
    ushort4 a = p0[(size_t)r.y * 256 + tid];
    ushort4 b = p1[(size_t)r.y * 256 + tid];
    float4  c = b4[(size_t)(r.y >> 10) * 256 + tid];
    res.x += g2 * (bf2f(a.x) + bf2f(b.x) + c.x);
    res.y += g2 * (bf2f(a.y) + bf2f(b.y) + c.y);
    res.z += g2 * (bf2f(a.z) + bf2f(b.z) + c.z);
    res.w += g2 * (bf2f(a.w) + bf2f(b.w) + c.w);
  }
  ((float4*)out)[(size_t)s * 256 + tid] = res;
}

// ---------- launcher ----------
extern "C" void kernel_launch(void* const* d_in, const int* in_sizes, int n_in,
                              void* d_out, int out_size, void* d_ws, size_t ws_size,
                              hipStream_t stream) {
  (void)in_sizes; (void)n_in; (void)out_size; (void)ws_size;
  const float* x  = (const float*)d_in[0];
  const float* wg = (const float*)d_in[1];
  const float* ew = (const float*)d_in[2];
  const float* eb = (const float*)d_in[3];
  float* out = (float*)d_out;

  char* ws = (char*)d_ws;
  // ws layout (bytes):
  //   [0,        8388608)  x bf16           [S][M]
  //   [8388608, 25165824)  W^T bf16         [E][N][M]
  //   [25165824,41943040)  eout partial kh=0 bf16 [E][C][N]
  //   [41943040,58720256)  eout partial kh=1 bf16 [E][C][N]
  //   [58720256,58722304)  zero row bf16    [1024]
  //   [58722304,58787840)  gate recs int4   [4096]
  //   [58787840,58853376)  token recs int4  [4096]
  //   [58853376,58886144)  slot_token int   [8192]
  //   [58886144,58918912)  gate partials    [1024][8] f32
  u16*   xbf   = (u16*)(ws + 0);
  u16*   wT    = (u16*)(ws + 8388608);
  u16*   eoutb = (u16*)(ws + 25165824);
  u16*   zrow  = (u16*)(ws + 58720256);
  int4*  grec  = (int4*)(ws + 58722304);
  int4*  trec  = (int4*)(ws + 58787840);
  int*   slot  = (int*)(ws + 58853376);
  float* gpart = (float*)(ws + 58886144);

  prep_kernel<<<3072, 256, 0, stream>>>(x, wg, ew, xbf, wT, grec, gpart);
  scan_kernel<<<1, 1024, 0, stream>>>(grec, trec, slot, gpart, zrow, out);
  expert_gemm<<<1024, 256, 0, stream>>>(xbf, wT, slot, zrow, eoutb);
  combine_kernel<<<4096, 256, 0, stream>>>(eoutb, trec, eb, out);
}